// Round 1
// baseline (711.844 us; speedup 1.0000x reference)
//
#include <hip/hip_runtime.h>
#include <hip/hip_bf16.h>

typedef __bf16 bf16x8 __attribute__((ext_vector_type(8)));
typedef float  f32x4  __attribute__((ext_vector_type(4)));

// One wave = 16 feature rows. Block = 4 waves = 64 rows. N % 64 == 0 (1e6 = 64*15625).
// A-fragment (mfma_f32_16x16x32_bf16): lane holds A[m=lane&15][k=(lane>>4)*8+j], j=0..7.
// C/D layout: col = lane&15, row = (lane>>4)*4 + reg  [learn_hip m89-verified].
__global__ __launch_bounds__(256) void proto_assign(
    const float* __restrict__ feat,
    const float* __restrict__ proto,
    float* __restrict__ logits,
    float* __restrict__ probs)
{
    const int lane = threadIdx.x & 63;
    const int wave = threadIdx.x >> 6;
    const int m    = lane & 15;
    const int q    = lane >> 4;

    // ---- B fragments: prototypes [K=64 protos][D=64], already unit-norm ----
    bf16x8 blo[4], bhi[4];
#pragma unroll
    for (int t = 0; t < 4; ++t) {
        const float* p = proto + (t * 16 + m) * 64 + q * 8;
        f32x4 p0 = *(const f32x4*)(p + 0);
        f32x4 p1 = *(const f32x4*)(p + 4);
        f32x4 p2 = *(const f32x4*)(p + 32);
        f32x4 p3 = *(const f32x4*)(p + 36);
#pragma unroll
        for (int i = 0; i < 4; ++i) {
            blo[t][i]     = (__bf16)p0[i];
            blo[t][4 + i] = (__bf16)p1[i];
            bhi[t][i]     = (__bf16)p2[i];
            bhi[t][4 + i] = (__bf16)p3[i];
        }
    }

    // ---- A: 16 feature rows, each lane loads its own fragment slots (fp32) ----
    const long long rowBase = (long long)blockIdx.x * 64 + wave * 16;
    const float* f = feat + (rowBase + m) * 64 + q * 8;
    f32x4 a0 = *(const f32x4*)(f + 0);
    f32x4 a1 = *(const f32x4*)(f + 4);
    f32x4 a2 = *(const f32x4*)(f + 32);
    f32x4 a3 = *(const f32x4*)(f + 36);

    // ---- L2 norm across the 4 q-groups holding this row ----
    float ss = 0.f;
#pragma unroll
    for (int i = 0; i < 4; ++i)
        ss += a0[i]*a0[i] + a1[i]*a1[i] + a2[i]*a2[i] + a3[i]*a3[i];
    ss += __shfl_xor(ss, 16);
    ss += __shfl_xor(ss, 32);
    // x / max(||x||, eps) then / tau  ==> scale = 5 / max(||x||, 1e-8)
    const float scale = 5.0f / fmaxf(sqrtf(ss), 1e-8f);

    bf16x8 alo, ahi;
#pragma unroll
    for (int i = 0; i < 4; ++i) {
        alo[i]     = (__bf16)(a0[i] * scale);
        alo[4 + i] = (__bf16)(a1[i] * scale);
        ahi[i]     = (__bf16)(a2[i] * scale);
        ahi[4 + i] = (__bf16)(a3[i] * scale);
    }

    // ---- 8 MFMAs: 16 rows x 64 protos, K=64 in two k-chunks ----
    f32x4 acc[4] = {};
#pragma unroll
    for (int t = 0; t < 4; ++t)
        acc[t] = __builtin_amdgcn_mfma_f32_16x16x32_bf16(alo, blo[t], acc[t], 0, 0, 0);
#pragma unroll
    for (int t = 0; t < 4; ++t)
        acc[t] = __builtin_amdgcn_mfma_f32_16x16x32_bf16(ahi, bhi[t], acc[t], 0, 0, 0);

    // ---- softmax over 64 cols: per-row values live in 16 lanes x 4 tiles ----
    float* lp = logits + rowBase * 64;
    float* pp = probs  + rowBase * 64;
#pragma unroll
    for (int j = 0; j < 4; ++j) {
        float l0 = acc[0][j], l1 = acc[1][j], l2 = acc[2][j], l3 = acc[3][j];
        float mx = fmaxf(fmaxf(l0, l1), fmaxf(l2, l3));
        mx = fmaxf(mx, __shfl_xor(mx, 1));
        mx = fmaxf(mx, __shfl_xor(mx, 2));
        mx = fmaxf(mx, __shfl_xor(mx, 4));
        mx = fmaxf(mx, __shfl_xor(mx, 8));
        float e0 = __expf(l0 - mx), e1 = __expf(l1 - mx),
              e2 = __expf(l2 - mx), e3 = __expf(l3 - mx);
        float s = e0 + e1 + e2 + e3;
        s += __shfl_xor(s, 1);
        s += __shfl_xor(s, 2);
        s += __shfl_xor(s, 4);
        s += __shfl_xor(s, 8);
        const float r = 1.0f / s;
        // output row = q*4 + j, col = t*16 + m
        const long long o = (long long)(q * 4 + j) * 64 + m;
        lp[o]      = l0;
        lp[o + 16] = l1;
        lp[o + 32] = l2;
        lp[o + 48] = l3;
        pp[o]      = e0 * r;
        pp[o + 16] = e1 * r;
        pp[o + 32] = e2 * r;
        pp[o + 48] = e3 * r;
    }
}

extern "C" void kernel_launch(void* const* d_in, const int* in_sizes, int n_in,
                              void* d_out, int out_size, void* d_ws, size_t ws_size,
                              hipStream_t stream) {
    const float* feat  = (const float*)d_in[0];
    const float* proto = (const float*)d_in[1];
    const int N = in_sizes[0] / 64;            // 1,000,000 rows; divisible by 64
    float* logits = (float*)d_out;
    float* probs  = logits + (long long)N * 64;
    proto_assign<<<N / 64, 256, 0, stream>>>(feat, proto, logits, probs);
}